// Round 7
// baseline (225.592 us; speedup 1.0000x reference)
//
#include <hip/hip_runtime.h>
#include <stdint.h>

typedef unsigned short u16;
typedef __attribute__((ext_vector_type(8))) short short8;
typedef __attribute__((ext_vector_type(4))) float floatx4;
typedef __attribute__((ext_vector_type(2))) float floatx2;

#define K_DIM 1024
#define N_DIM 1024
#define BM 64
#define BK 32
#define NCHUNK (K_DIM / BK)
#define HCHUNK (NCHUNK / 2)

__device__ __forceinline__ u16 f2b(float f) {
    union { float f; uint32_t i; } v; v.f = f;
    uint32_t u = v.i;
    return (u16)((u + 0x7FFFu + ((u >> 16) & 1u)) >> 16);   // RNE fp32->bf16
}
__device__ __forceinline__ float b2f(u16 u) {
    union { uint32_t i; float f; } v; v.i = ((uint32_t)u) << 16; return v.f;
}

// ---------- kernel 1: W fp32 -> bf16, packed in MFMA-fragment order ----------
__global__ __launch_bounds__(256) void pack_w_kernel(const float* __restrict__ w,
                                                     u16* __restrict__ wpk) {
    int gid  = blockIdx.x * 256 + threadIdx.x;   // 0..131071: (tile,kc,lane)
    int lane = gid & 63;
    int kc   = (gid >> 6) & 31;
    int tile = gid >> 11;                        // 0..63
    int n = tile * 16 + (lane & 15);
    int k = kc * 32 + (lane >> 4) * 8;
    const float* src = w + (size_t)n * K_DIM + k;
    floatx4 a = *(const floatx4*)(src);
    floatx4 b = *(const floatx4*)(src + 4);
    short8 o;
    o[0] = (short)f2b(a[0]); o[1] = (short)f2b(a[1]);
    o[2] = (short)f2b(a[2]); o[3] = (short)f2b(a[3]);
    o[4] = (short)f2b(b[0]); o[5] = (short)f2b(b[1]);
    o[6] = (short)f2b(b[2]); o[7] = (short)f2b(b[3]);
    *(short8*)(wpk + (size_t)gid * 8) = o;
}

// ---------- kernel 2a: GEMM + bias + row stats -> z(bf16) + mean/rstd --------
// R6's verified bulk-staged barrier-free K-loop. Epilogue writes bf16 z via the
// verified zbuf transpose (coalesced short8) and per-row mean/rstd to global.
// No y/out streaming here — that moves to the dedicated streaming kernel.
__global__ __launch_bounds__(1024) void gemm_stats_kernel(
    const float* __restrict__ x, const u16* __restrict__ wpk,
    const float* __restrict__ bias, u16* __restrict__ zout,
    float* __restrict__ stats)
{
    __shared__ __align__(16) u16 lds16[HCHUNK * BM * BK]; // 16 x 4KB A slabs (64KB)
    __shared__ __align__(16) u16 zbuf[16 * 1024];         // 32KB bf16 transpose buffer
    __shared__ float ls_sum[64];
    __shared__ float ls_sum2[64];

    const int tid  = threadIdx.x;
    const int lane = tid & 63;
    const int wv   = tid >> 6;            // 0..15
    const int q    = lane >> 4;           // quarter-wave id
    const int row0 = blockIdx.x * BM;

    if (tid < 64) { ls_sum[tid] = 0.0f; ls_sum2[tid] = 0.0f; }

    // ---- A staging addressing (verified): 2 fp32 per thread per chunk ----
    const int sr = tid >> 4;              // 0..63
    const int sk = (tid & 15) << 1;       // even 0..30
    const float* s_src = x + (size_t)(row0 + sr) * K_DIM + sk;
    const int s_qs  = (sk >> 3) ^ ((sr >> 1) & 3);
    const int s_off = sr * 64 + s_qs * 16 + (sk & 7) * 2;   // byte offset in 4KB slab

    // ---- B: packed fragment base; frag (ni,kc) at bp + ni*16384 + kc*512 ----
    const u16* bp = wpk + (size_t)wv * 65536 + lane * 8;

    // ---- A fragment LDS base offset within a slab (verified swizzle) ----
    const int a_base = (lane & 15) * 64 + (q ^ (((lane & 15) >> 1) & 3)) * 16;

    floatx4 acc[4][4];
#pragma unroll
    for (int mi = 0; mi < 4; ++mi)
#pragma unroll
        for (int ni = 0; ni < 4; ++ni)
            acc[mi][ni] = (floatx4){0.0f, 0.0f, 0.0f, 0.0f};

    // ---- prologue: bulk-stage A half 0 (chunks 0..15), prefetch B chunk 0 ----
#pragma unroll 4
    for (int c = 0; c < HCHUNK; ++c) {
        floatx2 v = *(const floatx2*)(s_src + c * BK);
        uint32_t p = (uint32_t)f2b(v[0]) | ((uint32_t)f2b(v[1]) << 16);
        *(uint32_t*)((char*)lds16 + c * 4096 + s_off) = p;
    }

    short8 bfr[2][4];
#pragma unroll
    for (int ni = 0; ni < 4; ++ni)
        bfr[0][ni] = *(const short8*)(bp + ni * 16384);     // kc=0

    __syncthreads();   // half-0 A staging visible; also covers ls_sum init

    for (int half = 0; half < 2; ++half) {
        if (half == 1) {
            __syncthreads();   // all waves done reading half-0 slabs
#pragma unroll 4
            for (int c = 0; c < HCHUNK; ++c) {
                floatx2 v = *(const floatx2*)(s_src + (HCHUNK + c) * BK);
                uint32_t p = (uint32_t)f2b(v[0]) | ((uint32_t)f2b(v[1]) << 16);
                *(uint32_t*)((char*)lds16 + c * 4096 + s_off) = p;
            }
            __syncthreads();   // half-1 staging visible
        }

#pragma unroll 2
        for (int c = 0; c < HCHUNK; ++c) {
            const int kc  = half * HCHUNK + c;
            const int cur = kc & 1;            // == c&1 (HCHUNK even): static
            const int nxt = cur ^ 1;
            const char* ab = (const char*)lds16 + c * 4096;

            short8 af0 = *(const short8*)(ab + a_base);
            short8 af1 = *(const short8*)(ab + a_base + 1024);
            short8 af2 = *(const short8*)(ab + a_base + 2048);
            short8 af3 = *(const short8*)(ab + a_base + 3072);

            const int kn = (kc + 1 < NCHUNK) ? (kc + 1) : kc;
#pragma unroll
            for (int ni = 0; ni < 4; ++ni)
                bfr[nxt][ni] = *(const short8*)(bp + ni * 16384 + kn * 512);

#pragma unroll
            for (int ni = 0; ni < 4; ++ni) {
                acc[0][ni] = __builtin_amdgcn_mfma_f32_16x16x32_bf16(
                    af0, bfr[cur][ni], acc[0][ni], 0, 0, 0);
                acc[1][ni] = __builtin_amdgcn_mfma_f32_16x16x32_bf16(
                    af1, bfr[cur][ni], acc[1][ni], 0, 0, 0);
                acc[2][ni] = __builtin_amdgcn_mfma_f32_16x16x32_bf16(
                    af2, bfr[cur][ni], acc[2][ni], 0, 0, 0);
                acc[3][ni] = __builtin_amdgcn_mfma_f32_16x16x32_bf16(
                    af3, bfr[cur][ni], acc[3][ni], 0, 0, 0);
            }
        }
    }

    // ---- bias (fp32) ----
    float bias_v[4];
#pragma unroll
    for (int ni = 0; ni < 4; ++ni)
        bias_v[ni] = bias[(wv << 6) + (ni << 4) + (lane & 15)];
#pragma unroll
    for (int mi = 0; mi < 4; ++mi)
#pragma unroll
        for (int ni = 0; ni < 4; ++ni)
#pragma unroll
            for (int r = 0; r < 4; ++r)
                acc[mi][ni][r] += bias_v[ni];

    __syncthreads();   // all waves past K-loop before stats atomics

    // ---- row stats: in-wave 64-col reduce, then LDS float atomics ----
#pragma unroll
    for (int mi = 0; mi < 4; ++mi)
#pragma unroll
        for (int r = 0; r < 4; ++r) {
            float s = 0.0f, s2 = 0.0f;
#pragma unroll
            for (int ni = 0; ni < 4; ++ni) {
                float v = acc[mi][ni][r];
                s += v; s2 += v * v;
            }
#pragma unroll
            for (int m = 1; m < 16; m <<= 1) {
                s  += __shfl_xor(s,  m, 64);
                s2 += __shfl_xor(s2, m, 64);
            }
            if ((lane & 15) == 0) {
                int rl = (mi << 4) + (q << 2) + r;       // C row = q*4 + r
                atomicAdd(&ls_sum[rl], s);
                atomicAdd(&ls_sum2[rl], s2);
            }
        }

    __syncthreads();
    if (tid < 64) {
        float mean = ls_sum[tid] * (1.0f / 1024.0f);
        float var  = ls_sum2[tid] * (1.0f / 1024.0f) - mean * mean;
        stats[row0 + tid]           = mean;
        stats[16384 + row0 + tid]   = rsqrtf(var + 1e-5f);
    }

    // ---- per 16-row slice: LDS transpose (bf16), coalesced z store ----
    for (int mi = 0; mi < 4; ++mi) {
#pragma unroll
        for (int ni = 0; ni < 4; ++ni)
#pragma unroll
            for (int r = 0; r < 4; ++r) {
                int lr   = (q << 2) + r;                          // local row 0..15
                int lin  = (((wv << 6) + (ni << 4) + (lane & 15)) << 1);
                int phys = lr * 2048 + (lin ^ (q << 5));          // swizzled
                *(u16*)((char*)zbuf + phys) = f2b(acc[mi][ni][r]);
            }
        __syncthreads();
#pragma unroll
        for (int it = 0; it < 2; ++it) {
            int row  = (tid >> 7) + (it << 3);                    // 0..15
            int c8   = tid & 127;                                 // 16B chunk id
            int phys = row * 2048 + ((c8 << 4) ^ (((row >> 2) & 3) << 5));
            short8 z8 = *(const short8*)((const char*)zbuf + phys);
            int grow  = row0 + (mi << 4) + row;
            *(short8*)(zout + (size_t)grow * N_DIM + c8 * 8) = z8;
        }
        __syncthreads();
    }
}

// ---------- kernel 2b: streaming LN apply: out = ((z-m)*rs*g + b + y)*y ------
// Pure memory-bound: 8192 blocks x 256 threads, each thread owns 8 cols of one
// row. z bf16 short8 + y/gamma/beta float4 + out float4: ~18B/elem traffic.
__global__ __launch_bounds__(256) void ln_apply_kernel(
    const u16* __restrict__ z, const float* __restrict__ y,
    const float* __restrict__ stats, const float* __restrict__ gamma,
    const float* __restrict__ beta, float* __restrict__ out)
{
    int g   = blockIdx.x * 256 + threadIdx.x;    // 0 .. 16384*128-1
    int row = g >> 7;
    int c8  = g & 127;
    float mean = stats[row];
    float rs   = stats[16384 + row];
    short8 z8 = *(const short8*)(z + (size_t)row * N_DIM + c8 * 8);
    const float* yp  = y     + (size_t)row * N_DIM + c8 * 8;
    const float* gp  = gamma + c8 * 8;
    const float* bpv = beta  + c8 * 8;
    float*       op  = out   + (size_t)row * N_DIM + c8 * 8;
    floatx4 y0 = *(const floatx4*)(yp);
    floatx4 y1 = *(const floatx4*)(yp + 4);
    floatx4 g0 = *(const floatx4*)(gp);
    floatx4 g1 = *(const floatx4*)(gp + 4);
    floatx4 b0 = *(const floatx4*)(bpv);
    floatx4 b1 = *(const floatx4*)(bpv + 4);
    floatx4 o0, o1;
#pragma unroll
    for (int e = 0; e < 4; ++e) {
        float zv = b2f((u16)z8[e]);
        o0[e] = ((zv - mean) * rs * g0[e] + b0[e] + y0[e]) * y0[e];
    }
#pragma unroll
    for (int e = 0; e < 4; ++e) {
        float zv = b2f((u16)z8[e + 4]);
        o1[e] = ((zv - mean) * rs * g1[e] + b1[e] + y1[e]) * y1[e];
    }
    *(floatx4*)(op)     = o0;
    *(floatx4*)(op + 4) = o1;
}

// ---------- fallback: R6 fused kernel (used only if workspace too small) -----
__global__ __launch_bounds__(1024) void fused_gemm_ln_kernel(
    const float* __restrict__ x, const float* __restrict__ y,
    const u16* __restrict__ wpk, const float* __restrict__ bias,
    const float* __restrict__ gamma, const float* __restrict__ beta,
    float* __restrict__ out)
{
    __shared__ __align__(16) u16 lds16[HCHUNK * BM * BK];
    __shared__ __align__(16) u16 zbuf[16 * 1024];
    __shared__ float ls_sum[64];
    __shared__ float ls_sum2[64];
    __shared__ float ls_mean[64];
    __shared__ float ls_rs[64];

    const int tid  = threadIdx.x;
    const int lane = tid & 63;
    const int wv   = tid >> 6;
    const int q    = lane >> 4;
    const int row0 = blockIdx.x * BM;

    if (tid < 64) { ls_sum[tid] = 0.0f; ls_sum2[tid] = 0.0f; }

    const int sr = tid >> 4;
    const int sk = (tid & 15) << 1;
    const float* s_src = x + (size_t)(row0 + sr) * K_DIM + sk;
    const int s_qs  = (sk >> 3) ^ ((sr >> 1) & 3);
    const int s_off = sr * 64 + s_qs * 16 + (sk & 7) * 2;

    const u16* bp = wpk + (size_t)wv * 65536 + lane * 8;
    const int a_base = (lane & 15) * 64 + (q ^ (((lane & 15) >> 1) & 3)) * 16;

    floatx4 acc[4][4];
#pragma unroll
    for (int mi = 0; mi < 4; ++mi)
#pragma unroll
        for (int ni = 0; ni < 4; ++ni)
            acc[mi][ni] = (floatx4){0.0f, 0.0f, 0.0f, 0.0f};

#pragma unroll 4
    for (int c = 0; c < HCHUNK; ++c) {
        floatx2 v = *(const floatx2*)(s_src + c * BK);
        uint32_t p = (uint32_t)f2b(v[0]) | ((uint32_t)f2b(v[1]) << 16);
        *(uint32_t*)((char*)lds16 + c * 4096 + s_off) = p;
    }
    short8 bfr[2][4];
#pragma unroll
    for (int ni = 0; ni < 4; ++ni)
        bfr[0][ni] = *(const short8*)(bp + ni * 16384);
    __syncthreads();

    for (int half = 0; half < 2; ++half) {
        if (half == 1) {
            __syncthreads();
#pragma unroll 4
            for (int c = 0; c < HCHUNK; ++c) {
                floatx2 v = *(const floatx2*)(s_src + (HCHUNK + c) * BK);
                uint32_t p = (uint32_t)f2b(v[0]) | ((uint32_t)f2b(v[1]) << 16);
                *(uint32_t*)((char*)lds16 + c * 4096 + s_off) = p;
            }
            __syncthreads();
        }
#pragma unroll 2
        for (int c = 0; c < HCHUNK; ++c) {
            const int kc  = half * HCHUNK + c;
            const int cur = kc & 1;
            const int nxt = cur ^ 1;
            const char* ab = (const char*)lds16 + c * 4096;
            short8 af0 = *(const short8*)(ab + a_base);
            short8 af1 = *(const short8*)(ab + a_base + 1024);
            short8 af2 = *(const short8*)(ab + a_base + 2048);
            short8 af3 = *(const short8*)(ab + a_base + 3072);
            const int kn = (kc + 1 < NCHUNK) ? (kc + 1) : kc;
#pragma unroll
            for (int ni = 0; ni < 4; ++ni)
                bfr[nxt][ni] = *(const short8*)(bp + ni * 16384 + kn * 512);
#pragma unroll
            for (int ni = 0; ni < 4; ++ni) {
                acc[0][ni] = __builtin_amdgcn_mfma_f32_16x16x32_bf16(
                    af0, bfr[cur][ni], acc[0][ni], 0, 0, 0);
                acc[1][ni] = __builtin_amdgcn_mfma_f32_16x16x32_bf16(
                    af1, bfr[cur][ni], acc[1][ni], 0, 0, 0);
                acc[2][ni] = __builtin_amdgcn_mfma_f32_16x16x32_bf16(
                    af2, bfr[cur][ni], acc[2][ni], 0, 0, 0);
                acc[3][ni] = __builtin_amdgcn_mfma_f32_16x16x32_bf16(
                    af3, bfr[cur][ni], acc[3][ni], 0, 0, 0);
            }
        }
    }

    float bias_v[4];
#pragma unroll
    for (int ni = 0; ni < 4; ++ni)
        bias_v[ni] = bias[(wv << 6) + (ni << 4) + (lane & 15)];
#pragma unroll
    for (int mi = 0; mi < 4; ++mi)
#pragma unroll
        for (int ni = 0; ni < 4; ++ni)
#pragma unroll
            for (int r = 0; r < 4; ++r)
                acc[mi][ni][r] += bias_v[ni];

    __syncthreads();

#pragma unroll
    for (int mi = 0; mi < 4; ++mi)
#pragma unroll
        for (int r = 0; r < 4; ++r) {
            float s = 0.0f, s2 = 0.0f;
#pragma unroll
            for (int ni = 0; ni < 4; ++ni) {
                float v = acc[mi][ni][r];
                s += v; s2 += v * v;
            }
#pragma unroll
            for (int m = 1; m < 16; m <<= 1) {
                s  += __shfl_xor(s,  m, 64);
                s2 += __shfl_xor(s2, m, 64);
            }
            if ((lane & 15) == 0) {
                int rl = (mi << 4) + (q << 2) + r;
                atomicAdd(&ls_sum[rl], s);
                atomicAdd(&ls_sum2[rl], s2);
            }
        }

    __syncthreads();
    if (tid < 64) {
        float mean = ls_sum[tid] * (1.0f / 1024.0f);
        float var  = ls_sum2[tid] * (1.0f / 1024.0f) - mean * mean;
        ls_mean[tid] = mean;
        ls_rs[tid]   = rsqrtf(var + 1e-5f);
    }

    for (int mi = 0; mi < 4; ++mi) {
#pragma unroll
        for (int ni = 0; ni < 4; ++ni)
#pragma unroll
            for (int r = 0; r < 4; ++r) {
                int lr   = (q << 2) + r;
                int lin  = (((wv << 6) + (ni << 4) + (lane & 15)) << 1);
                int phys = lr * 2048 + (lin ^ (q << 5));
                *(u16*)((char*)zbuf + phys) = f2b(acc[mi][ni][r]);
            }
        __syncthreads();
#pragma unroll
        for (int it = 0; it < 2; ++it) {
            int row  = (tid >> 7) + (it << 3);
            int c8   = tid & 127;
            int phys = row * 2048 + ((c8 << 4) ^ (((row >> 2) & 3) << 5));
            short8 z8 = *(const short8*)((const char*)zbuf + phys);
            int grow  = row0 + (mi << 4) + row;
            float mean = ls_mean[(mi << 4) + row];
            float rs   = ls_rs[(mi << 4) + row];
            const float* yp = y     + (size_t)grow * N_DIM + c8 * 8;
            const float* gp = gamma + c8 * 8;
            const float* bpv = beta + c8 * 8;
            float*       op = out   + (size_t)grow * N_DIM + c8 * 8;
            floatx4 y0 = *(const floatx4*)(yp);
            floatx4 y1 = *(const floatx4*)(yp + 4);
            floatx4 g0 = *(const floatx4*)(gp);
            floatx4 g1 = *(const floatx4*)(gp + 4);
            floatx4 b0 = *(const floatx4*)(bpv);
            floatx4 b1 = *(const floatx4*)(bpv + 4);
            floatx4 o0, o1;
#pragma unroll
            for (int e = 0; e < 4; ++e) {
                float zv = b2f((u16)z8[e]);
                o0[e] = ((zv - mean) * rs * g0[e] + b0[e] + y0[e]) * y0[e];
            }
#pragma unroll
            for (int e = 0; e < 4; ++e) {
                float zv = b2f((u16)z8[e + 4]);
                o1[e] = ((zv - mean) * rs * g1[e] + b1[e] + y1[e]) * y1[e];
            }
            *(floatx4*)(op)     = o0;
            *(floatx4*)(op + 4) = o1;
        }
        __syncthreads();
    }
}

extern "C" void kernel_launch(void* const* d_in, const int* in_sizes, int n_in,
                              void* d_out, int out_size, void* d_ws, size_t ws_size,
                              hipStream_t stream) {
    const float* x     = (const float*)d_in[0];
    const float* y     = (const float*)d_in[1];
    const float* wgt   = (const float*)d_in[2];
    const float* bias  = (const float*)d_in[3];
    const float* gamma = (const float*)d_in[4];
    const float* beta  = (const float*)d_in[5];
    float* out = (float*)d_out;

    u16* wpk = (u16*)d_ws;                               // 2MB packed bf16 W
    const size_t WPK_BYTES   = 2u * 1024u * 1024u;
    const size_t STATS_BYTES = 128u * 1024u;             // 2 x 16384 fp32
    const size_t Z_BYTES     = 32u * 1024u * 1024u;      // 16384x1024 bf16
    const int M = in_sizes[0] / K_DIM;                   // 16384

    pack_w_kernel<<<512, 256, 0, stream>>>(wgt, wpk);

    if (ws_size >= WPK_BYTES + STATS_BYTES + Z_BYTES) {
        float* stats = (float*)((char*)d_ws + WPK_BYTES);
        u16*   zws   = (u16*)((char*)d_ws + WPK_BYTES + STATS_BYTES);
        gemm_stats_kernel<<<M / BM, 1024, 0, stream>>>(x, wpk, bias, zws, stats);
        ln_apply_kernel<<<M * (N_DIM / 8) / 256, 256, 0, stream>>>(
            zws, y, stats, gamma, beta, out);
    } else {
        fused_gemm_ln_kernel<<<M / BM, 1024, 0, stream>>>(
            x, y, wpk, bias, gamma, beta, out);
    }
}